// Round 12
// baseline (286.576 us; speedup 1.0000x reference)
//
#include <hip/hip_runtime.h>
#include <stdint.h>

typedef _Float16 f16;
typedef _Float16 f16x8 __attribute__((ext_vector_type(8)));
typedef _Float16 f16x4 __attribute__((ext_vector_type(4)));
typedef float f32x4 __attribute__((ext_vector_type(4)));
typedef int   i32x4 __attribute__((ext_vector_type(4)));

#define S_TOK 8192
#define DDIM  512
#define L2E   1.44269504088896340736f
#define QSCALE 0.04419417382415922f   // 1/sqrt(512)
#define NSLOT 320
#define GTOT  8320                    // total KVB=32 iterations over all 64 tiles

__device__ __forceinline__ void gload_lds16(const void* g, void* l) {
  __builtin_amdgcn_global_load_lds((const __attribute__((address_space(1))) void*)g,
                                   (__attribute__((address_space(3))) void*)l, 16, 0, 0);
}

// DPP 16-lane (row) reductions — pure VALU, no LDS pipe.
template <int C>
__device__ __forceinline__ float fdpp(float x) {
  return __builtin_bit_cast(float,
      __builtin_amdgcn_update_dpp(0, __builtin_bit_cast(int, x), C, 0xF, 0xF, true));
}
__device__ __forceinline__ float rowmax16(float x) {
  x = fmaxf(x, fdpp<0xB1>(x));    // quad_perm [1,0,3,2]  (xor1)
  x = fmaxf(x, fdpp<0x4E>(x));    // quad_perm [2,3,0,1]  (xor2)
  x = fmaxf(x, fdpp<0x141>(x));   // row_half_mirror
  x = fmaxf(x, fdpp<0x140>(x));   // row_mirror
  return x;
}
__device__ __forceinline__ float rowsum16(float x) {
  x += fdpp<0xB1>(x);
  x += fdpp<0x4E>(x);
  x += fdpp<0x141>(x);
  x += fdpp<0x140>(x);
  return x;
}

// ---------------- convert f32 -> f16 (+ slot-table init) ------------------
__global__ __launch_bounds__(256) void k_convert(
    const float* __restrict__ X, const float* __restrict__ Wq,
    const float* __restrict__ Wk, const float* __restrict__ Wv,
    f16* __restrict__ Xh, f16* __restrict__ Wh, int* __restrict__ tp) {
  const int SD = S_TOK * DDIM;
  const int DD = DDIM * DDIM;
  int gi = blockIdx.x * 256 + threadIdx.x;
  if (gi < NSLOT) tp[gi] = -1;
  int i4 = gi * 4;
  if (i4 < SD) {
    f32x4 v = *(const f32x4*)(X + i4);
    f16x4 h = {(f16)v[0], (f16)v[1], (f16)v[2], (f16)v[3]};
    *(f16x4*)(Xh + i4) = h;
  } else {
    int j = i4 - SD;
    int mat = j >> 18;
    const float* src = (mat == 0) ? Wq : (mat == 1 ? Wk : Wv);
    f32x4 v = *(const f32x4*)(src + (j & (DD - 1)));
    f16x4 h = {(f16)v[0], (f16)v[1], (f16)v[2], (f16)v[3]};
    *(f16x4*)(Wh + j) = h;
  }
}

// ---------------- QKV projection ------------------------------------------
// Q row-major (pre-scaled).
// K in QKT-B-frag order: tile*32768 + half*16384 + ks*1024 + lane*16 + j*2
//   holds K[tile*32 + half*16 + (lane&15)][ks*32 + (lane>>4)*8 + j]
// V in PV-B-frag order: (K*32+f)*1024 + lane*16 + j*2 holds
//   V[K*32+(lane>>4)*8+j][f*16+(lane&15)]
__global__ __launch_bounds__(256) void k_proj(
    const f16* __restrict__ Xh, const f16* __restrict__ Wh,
    f16* __restrict__ Qh, f16* __restrict__ KB, f16* __restrict__ VB) {
  __shared__ __align__(16) char Al[128 * 128];
  __shared__ __align__(16) char Bl[128 * 128];
  const int tid = threadIdx.x;
  const int w = tid >> 6, lane = tid & 63;
  const int m0 = blockIdx.x * 128;
  const int n0 = blockIdx.y * 128;
  const int wr = (w >> 1) * 64;
  const int wc = (w & 1) * 64;

  f32x4 acc[4][4];
#pragma unroll
  for (int i = 0; i < 4; ++i)
#pragma unroll
    for (int j = 0; j < 4; ++j) acc[i][j] = (f32x4){0.f, 0.f, 0.f, 0.f};

  const char* Xb = (const char*)Xh;
  const char* Wb = (const char*)Wh;

  for (int kb = 0; kb < DDIM; kb += 64) {
    __syncthreads();
#pragma unroll
    for (int i = 0; i < 4; ++i) {
      int ch = w * 4 + i;
      int srow = lane >> 3;
      int scol = ((lane & 7) * 16) ^ (srow << 4);
      gload_lds16(Xb + (size_t)(m0 + ch * 8 + srow) * 1024 + kb * 2 + scol, Al + ch * 1024);
      gload_lds16(Wb + (size_t)(n0 + ch * 8 + srow) * 1024 + kb * 2 + scol, Bl + ch * 1024);
    }
    __syncthreads();
#pragma unroll
    for (int ks = 0; ks < 2; ++ks) {
      f16x8 a[4], b[4];
#pragma unroll
      for (int mf = 0; mf < 4; ++mf) {
        int row = wr + mf * 16 + (lane & 15);
        int col = (ks * 64 + ((lane >> 4) * 16)) ^ ((row & 7) << 4);
        a[mf] = *(const f16x8*)(Al + row * 128 + col);
      }
#pragma unroll
      for (int nf = 0; nf < 4; ++nf) {
        int row = wc + nf * 16 + (lane & 15);
        int col = (ks * 64 + ((lane >> 4) * 16)) ^ ((row & 7) << 4);
        b[nf] = *(const f16x8*)(Bl + row * 128 + col);
      }
#pragma unroll
      for (int mf = 0; mf < 4; ++mf)
#pragma unroll
        for (int nf = 0; nf < 4; ++nf)
          acc[mf][nf] = __builtin_amdgcn_mfma_f32_16x16x32_f16(a[mf], b[nf], acc[mf][nf], 0, 0, 0);
    }
  }
  int mat = n0 >> 9;
  int nbase = n0 & 511;
  if (mat == 2) {
#pragma unroll
    for (int mf = 0; mf < 4; ++mf) {
      int R0 = m0 + wr + mf * 16 + (lane >> 4) * 4;   // 4-aligned token row
      int K = R0 >> 5;
      int lhi = ((R0 >> 3) & 3) * 16;
      int j0 = R0 & 7;                                // 0 or 4
#pragma unroll
      for (int nf = 0; nf < 4; ++nf) {
        int col = nbase + wc + nf * 16 + (lane & 15);
        f16x4 h = {(f16)acc[mf][nf][0], (f16)acc[mf][nf][1],
                   (f16)acc[mf][nf][2], (f16)acc[mf][nf][3]};
        *(f16x4*)((char*)VB + (size_t)(K * 32 + (col >> 4)) * 1024 +
                  (lhi + (col & 15)) * 16 + j0 * 2) = h;
      }
    }
  } else if (mat == 1) {
#pragma unroll
    for (int mf = 0; mf < 4; ++mf)
#pragma unroll
      for (int nf = 0; nf < 4; ++nf)
#pragma unroll
        for (int r = 0; r < 4; ++r) {
          int token = m0 + wr + mf * 16 + (lane >> 4) * 4 + r;
          int d = nbase + wc + nf * 16 + (lane & 15);
          size_t byte = (size_t)(token >> 5) * 32768 + (size_t)((token >> 4) & 1) * 16384
                      + (size_t)(d >> 5) * 1024
                      + (token & 15) * 16 + ((d >> 3) & 3) * 256 + (d & 7) * 2;
          *(f16*)((char*)KB + byte) = (f16)acc[mf][nf][r];
        }
  } else {
    float scale = QSCALE;
#pragma unroll
    for (int mf = 0; mf < 4; ++mf)
#pragma unroll
      for (int nf = 0; nf < 4; ++nf)
#pragma unroll
        for (int r = 0; r < 4; ++r) {
          int row = m0 + wr + mf * 16 + (lane >> 4) * 4 + r;
          int col = nbase + wc + nf * 16 + (lane & 15);
          Qh[(size_t)row * DDIM + col] = (f16)(acc[mf][nf][r] * scale);
        }
  }
}

// ---------------- causal flash attention, v12 ------------------------------
// R11 + d-split PV with SHARED P: wave w computes O[all 128 rows x 64-col
// slice] so it reads only its 4 V frags (4KB) instead of the whole 32KB V
// tile. P[128x32] shared LDS, stride-72 rows (conflict-free write + b128
// A-frag read). Per iter: stage(it+1) -> QKT(it) -> SM(it)->P,Al,Fl ->
// lgkm+barrier -> rescale?+PV(it) -> vmcnt(0) -> barrier.
__global__ __launch_bounds__(512, 2) void k_flash(
    const f16* __restrict__ Qh, const f16* __restrict__ KBg,
    const f16* __restrict__ VBg, f16* __restrict__ Opart,
    float* __restrict__ Mpart, float* __restrict__ Lpart,
    int* __restrict__ TilePart) {
  __shared__ __align__(16) char Kl[2][32768];   // K tile, frag-packed (linear)
  __shared__ __align__(16) char Vl[2][32768];   // V frag-packed [32 frags][1KB]
  __shared__ __align__(16) char Pl[2][9216];    // shared P: 128 rows x 72B, dbuf
  __shared__ __align__(16) float Alph[128];     // per-row rescale alpha
  __shared__ __align__(16) float Ll[128];       // per-row l (epilogue)
  __shared__ __align__(16) int Fl[8];           // per-wave rescale flags

  const int tid = threadIdx.x;
  const int w = tid >> 6, lane = tid & 63;
  const int l15 = lane & 15, l4 = lane >> 4;

  int bid = blockIdx.x;
  int b = (bid & 7) * 32 + (bid >> 3);          // XCD-contiguous logical id
  int g  = (GTOT * b) >> 8;
  int g1 = (GTOT * (b + 1)) >> 8;
  int t = 0;
  while (2 * (t + 1) * (t + 2) <= g) ++t;

  const char* Kb = (const char*)KBg;
  const char* Vb = (const char*)VBg;

#define STAGEKV(KB_, BI) do {                                                  \
    const char* ks_ = Kb + (size_t)((KB_) >> 5) * 32768;                       \
    _Pragma("unroll")                                                          \
    for (int i_ = 0; i_ < 4; ++i_) {                                           \
      int ch_ = w * 4 + i_;                                                    \
      gload_lds16(ks_ + ch_ * 1024 + lane * 16, Kl[BI] + ch_ * 1024);          \
    }                                                                          \
    const char* vs_ = Vb + (size_t)(KB_) * 1024;                               \
    _Pragma("unroll")                                                          \
    for (int i_ = 0; i_ < 4; ++i_) {                                           \
      int ch_ = w * 4 + i_;                                                    \
      gload_lds16(vs_ + ch_ * 1024 + lane * 16, Vl[BI] + ch_ * 1024);          \
    } } while (0)

// softmax of s0/s1 for kv block KB_; P (rows w*16..) into shared Pdst;
// always writes Alph (1.0 when no rescale), Fl[w] = need.
#define SOFTMAX(KB_, Pdst) do {                                                \
    float p0[4], p1[4], mx[4], alpha[4];                                       \
    int qrb = q0 + w * 16 + l4 * 4;                                            \
    int kc = (KB_) + l15;                                                      \
    _Pragma("unroll")                                                          \
    for (int r = 0; r < 4; ++r) {                                              \
      int qr = qrb + r;                                                        \
      float x0 = (kc      <= qr) ? s0[r] : -3.0e38f;                           \
      float x1 = (kc + 16 <= qr) ? s1[r] : -3.0e38f;                           \
      p0[r] = x0; p1[r] = x1;                                                  \
      mx[r] = rowmax16(fmaxf(x0, x1));                                         \
    }                                                                          \
    bool need = (mx[0] > mreg[0] + 8.f) || (mx[1] > mreg[1] + 8.f) ||          \
                (mx[2] > mreg[2] + 8.f) || (mx[3] > mreg[3] + 8.f);            \
    need = __any(need);                                                        \
    if (need) {                                                                \
      _Pragma("unroll")                                                        \
      for (int r = 0; r < 4; ++r) {                                            \
        float mn = fmaxf(mreg[r], mx[r]);                                      \
        alpha[r] = exp2f((mreg[r] - mn) * L2E);                                \
        lreg[r] *= alpha[r];                                                   \
        mreg[r] = mn;                                                          \
      }                                                                        \
    } else {                                                                   \
      _Pragma("unroll")                                                        \
      for (int r = 0; r < 4; ++r) alpha[r] = 1.0f;                             \
    }                                                                          \
    if (l15 == 0) {                                                            \
      _Pragma("unroll")                                                        \
      for (int r = 0; r < 4; ++r) Alph[w * 16 + l4 * 4 + r] = alpha[r];        \
    }                                                                          \
    if (lane == 0) Fl[w] = need ? 1 : 0;                                       \
    _Pragma("unroll")                                                          \
    for (int r = 0; r < 4; ++r) {                                              \
      int qr = qrb + r;                                                        \
      p0[r] = (kc      <= qr) ? exp2f((p0[r] - mreg[r]) * L2E) : 0.f;          \
      p1[r] = (kc + 16 <= qr) ? exp2f((p1[r] - mreg[r]) * L2E) : 0.f;          \
    }                                                                          \
    _Pragma("unroll")                                                          \
    for (int r = 0; r < 4; ++r) {                                              \
      int row = w * 16 + l4 * 4 + r;                                           \
      *(f16*)((Pdst) + row * 72 + l15 * 2)      = (f16)p0[r];                  \
      *(f16*)((Pdst) + row * 72 + 32 + l15 * 2) = (f16)p1[r];                  \
    }                                                                          \
    _Pragma("unroll")                                                          \
    for (int r = 0; r < 4; ++r)                                                \
      lreg[r] += rowsum16(p0[r] + p1[r]);                                      \
  } while (0)

// QKT: frag-packed K -> one base register, all offsets immediate
#define QKT(BUF) do {                                                          \
    s0 = (f32x4){0.f, 0.f, 0.f, 0.f};                                          \
    s1 = (f32x4){0.f, 0.f, 0.f, 0.f};                                          \
    const char* kp_ = (BUF) + lane * 16;                                       \
    __builtin_amdgcn_s_setprio(1);                                             \
    _Pragma("unroll")                                                          \
    for (int ks = 0; ks < 16; ++ks) {                                          \
      f16x8 kf0 = *(const f16x8*)(kp_ + ks * 1024);                            \
      s0 = __builtin_amdgcn_mfma_f32_16x16x32_f16(qf[ks], kf0, s0, 0, 0, 0);   \
      f16x8 kf1 = *(const f16x8*)(kp_ + 16384 + ks * 1024);                    \
      s1 = __builtin_amdgcn_mfma_f32_16x16x32_f16(qf[ks], kf1, s1, 0, 0, 0);   \
    }                                                                          \
    __builtin_amdgcn_s_setprio(0); } while (0)

// PV d-split: rescale (block-rare) then O[128 x 64-slice] += P @ V-slice
#define PV(BI) do {                                                            \
    i32x4 f0_ = *(const i32x4*)(Fl);                                           \
    i32x4 f1_ = *(const i32x4*)(Fl + 4);                                       \
    int fl_ = f0_[0] | f0_[1] | f0_[2] | f0_[3] | f1_[0] | f1_[1] | f1_[2] | f1_[3]; \
    if (fl_) {                                                                 \
      _Pragma("unroll")                                                        \
      for (int rf = 0; rf < 8; ++rf) {                                         \
        f32x4 av_ = *(const f32x4*)(Alph + rf * 16 + l4 * 4);                  \
        _Pragma("unroll")                                                      \
        for (int cf = 0; cf < 4; ++cf) {                                       \
          acc[rf * 4 + cf][0] *= av_[0];                                       \
          acc[rf * 4 + cf][1] *= av_[1];                                       \
          acc[rf * 4 + cf][2] *= av_[2];                                       \
          acc[rf * 4 + cf][3] *= av_[3];                                       \
        }                                                                      \
      }                                                                        \
    }                                                                          \
    f16x8 vbf_[4];                                                             \
    _Pragma("unroll")                                                          \
    for (int cf = 0; cf < 4; ++cf)                                             \
      vbf_[cf] = *(const f16x8*)(Vl[BI] + (w * 4 + cf) * 1024 + lane * 16);    \
    const char* pb_ = Pl[BI] + l15 * 72 + l4 * 16;                             \
    __builtin_amdgcn_s_setprio(1);                                             \
    _Pragma("unroll")                                                          \
    for (int rf = 0; rf < 8; ++rf) {                                           \
      f16x8 pa_ = *(const f16x8*)(pb_ + rf * 1152);                            \
      _Pragma("unroll")                                                        \
      for (int cf = 0; cf < 4; ++cf)                                           \
        acc[rf * 4 + cf] = __builtin_amdgcn_mfma_f32_16x16x32_f16(pa_, vbf_[cf], acc[rf * 4 + cf], 0, 0, 0); \
    }                                                                          \
    __builtin_amdgcn_s_setprio(0); } while (0)

  while (g < g1) {
    int Ct  = 2 * t * (t + 1);
    int Ct1 = 2 * (t + 1) * (t + 2);
    int gend = min(g1, Ct1);
    int n = gend - g;
    int kb0 = (g - Ct) * 32;
    int q0 = t * 128;
    int slot = b + t;

    // Q fragments: rows q0 + w*16 + l15, full D
    f16x8 qf[16];
    {
      const f16* qp = Qh + (size_t)(q0 + w * 16 + l15) * DDIM + l4 * 8;
#pragma unroll
      for (int ks = 0; ks < 16; ++ks) qf[ks] = *(const f16x8*)(qp + ks * 32);
    }
    f32x4 acc[32];     // acc[rf*4+cf] = O[rf*16 + l4*4 + r][w*64 + cf*16 + l15]
#pragma unroll
    for (int i = 0; i < 32; ++i) acc[i] = (f32x4){0.f, 0.f, 0.f, 0.f};
    float mreg[4], lreg[4];
#pragma unroll
    for (int r = 0; r < 4; ++r) { mreg[r] = -3.0e38f; lreg[r] = 0.f; }
    f32x4 s0, s1;

    // ---- prologue
    STAGEKV(kb0, 0);
    asm volatile("s_waitcnt vmcnt(0)" ::: "memory");
    __builtin_amdgcn_s_barrier();

    for (int it = 0; it < n; ++it) {
      int cur = it & 1;
      if (it + 1 < n) STAGEKV(kb0 + (it + 1) * 32, cur ^ 1);
      QKT(Kl[cur]);
      SOFTMAX(kb0 + it * 32, Pl[cur]);
      asm volatile("s_waitcnt lgkmcnt(0)" ::: "memory");  // P/Alph/Fl committed
      __builtin_amdgcn_s_barrier();                       // publish P(it)
      PV(cur);
      asm volatile("s_waitcnt vmcnt(0)" ::: "memory");    // stage(it+1) landed
      __builtin_amdgcn_s_barrier();                       // publish K/V(it+1)
    }

    // ---- epilogue: share l, write partial (O rows all 128, cols w*64..)
    if (l15 == 0) {
#pragma unroll
      for (int r = 0; r < 4; ++r) Ll[w * 16 + l4 * 4 + r] = lreg[r];
    }
    asm volatile("s_waitcnt lgkmcnt(0)" ::: "memory");
    __builtin_amdgcn_s_barrier();
    {
      f16* op = Opart + (size_t)slot * (128 * 512);
#pragma unroll
      for (int rf = 0; rf < 8; ++rf) {
        f32x4 lv = *(const f32x4*)(Ll + rf * 16 + l4 * 4);
        f32x4 inv;
#pragma unroll
        for (int r = 0; r < 4; ++r) inv[r] = (lv[r] > 0.f) ? 1.f / lv[r] : 0.f;
#pragma unroll
        for (int cf = 0; cf < 4; ++cf) {
          int col = w * 64 + cf * 16 + l15;
#pragma unroll
          for (int r = 0; r < 4; ++r) {
            int row = rf * 16 + l4 * 4 + r;
            op[(size_t)row * 512 + col] = (f16)(acc[rf * 4 + cf][r] * inv[r]);
          }
        }
      }
      if (l15 == 0) {
#pragma unroll
        for (int r = 0; r < 4; ++r) {
          int row = w * 16 + l4 * 4 + r;
          Mpart[slot * 128 + row] = mreg[r];
          Lpart[slot * 128 + row] = lreg[r];
        }
      }
      if (tid == 0) TilePart[slot] = t;
    }
    __builtin_amdgcn_s_barrier();   // Ll reads done before next tile reuses it
    g = gend;
    ++t;
  }
#undef STAGEKV
#undef SOFTMAX
#undef QKT
#undef PV
}

// ---------------- combine partials -> out --------------------------------
__global__ __launch_bounds__(256) void k_reduce(
    const f16* __restrict__ Opart, const float* __restrict__ Mpart,
    const float* __restrict__ Lpart, const int* __restrict__ TilePart,
    float* __restrict__ out) {
  __shared__ int tp[NSLOT];
  __shared__ int sl[16];
  __shared__ int scnt;
  int tid = threadIdx.x;
  int t = blockIdx.x >> 2, rg = blockIdx.x & 3;
  for (int s = tid; s < NSLOT; s += 256) tp[s] = TilePart[s];
  __syncthreads();
  if (tid == 0) {
    int c = 0;
    for (int s = 0; s < NSLOT; ++s)
      if (tp[s] == t && c < 16) sl[c++] = s;
    scnt = c;
  }
  __syncthreads();
  int cnt = scnt;
  int rowIn = rg * 32 + (tid >> 3);
  int row = t * 128 + rowIn;
  int col0 = (tid & 7) * 64;

  float M = -3.0e38f;
  for (int i = 0; i < cnt; ++i) M = fmaxf(M, Mpart[sl[i] * 128 + rowIn]);
  float a[64];
#pragma unroll
  for (int j = 0; j < 64; ++j) a[j] = 0.f;
  float denom = 0.f;
  for (int i = 0; i < cnt; ++i) {
    int s = sl[i];
    float m = Mpart[s * 128 + rowIn];
    float l = Lpart[s * 128 + rowIn];
    float wgt = exp2f((m - M) * L2E) * l;
    denom += wgt;
    const f16* op = Opart + (size_t)s * 65536 + rowIn * 512 + col0;
#pragma unroll
    for (int v = 0; v < 8; ++v) {
      f16x8 x = *(const f16x8*)(op + v * 8);
#pragma unroll
      for (int j = 0; j < 8; ++j) a[v * 8 + j] += wgt * (float)x[j];
    }
  }
  float inv = (denom > 0.f) ? 1.f / denom : 0.f;
  float* o = out + (size_t)row * 512 + col0;
#pragma unroll
  for (int j = 0; j < 64; ++j) o[j] = a[j] * inv;
}

extern "C" void kernel_launch(void* const* d_in, const int* in_sizes, int n_in,
                              void* d_out, int out_size, void* d_ws, size_t ws_size,
                              hipStream_t stream) {
  const float* X  = (const float*)d_in[0];
  const float* Wq = (const float*)d_in[2];
  const float* Wk = (const float*)d_in[3];
  const float* Wv = (const float*)d_in[4];
  float* out = (float*)d_out;

  char* ws = (char*)d_ws;
  f16*   Opart = (f16*)(ws);                               // 40 MiB
  float* Mpart = (float*)(ws + (40u << 20));               // 160 KiB
  float* Lpart = (float*)(ws + (41u << 20));               // 160 KiB
  int*   TileP = (int*)(ws + (42u << 20));                 // 1.25 KiB
  f16* Qh = (f16*)(ws + (43u << 20));                      // 8 MiB (pre-scaled)
  f16* KB = (f16*)(ws + (51u << 20));                      // 8 MiB QKT-frag-packed
  f16* VB = (f16*)(ws + (59u << 20));                      // 8 MiB PV-frag-packed
  f16* Xh = (f16*)(ws + (67u << 20));                      // 8 MiB
  f16* Wh = (f16*)(ws + (75u << 20));                      // 1.5 MiB

  k_convert<<<4864, 256, 0, stream>>>(X, Wq, Wk, Wv, Xh, Wh, TileP);
  dim3 gp(64, 12);
  k_proj<<<gp, 256, 0, stream>>>(Xh, Wh, Qh, KB, VB);
  k_flash<<<256, 512, 0, stream>>>(Qh, KB, VB, Opart, Mpart, Lpart, TileP);
  k_reduce<<<256, 256, 0, stream>>>(Opart, Mpart, Lpart, TileP, out);
}

// Round 13
// 212.346 us; speedup vs baseline: 1.3496x; 1.3496x over previous
//
#include <hip/hip_runtime.h>
#include <stdint.h>

typedef _Float16 f16;
typedef _Float16 f16x8 __attribute__((ext_vector_type(8)));
typedef _Float16 f16x4 __attribute__((ext_vector_type(4)));
typedef float f32x4 __attribute__((ext_vector_type(4)));

#define S_TOK 8192
#define DDIM  512
#define L2E   1.44269504088896340736f
#define QSCALE 0.04419417382415922f   // 1/sqrt(512)
#define NSLOT 320
#define GTOT  8320                    // total KVB=32 iterations over all 64 tiles

__device__ __forceinline__ void gload_lds16(const void* g, void* l) {
  __builtin_amdgcn_global_load_lds((const __attribute__((address_space(1))) void*)g,
                                   (__attribute__((address_space(3))) void*)l, 16, 0, 0);
}

// DPP 16-lane (row) reductions — pure VALU, no LDS pipe.
template <int C>
__device__ __forceinline__ float fdpp(float x) {
  return __builtin_bit_cast(float,
      __builtin_amdgcn_update_dpp(0, __builtin_bit_cast(int, x), C, 0xF, 0xF, true));
}
__device__ __forceinline__ float rowmax16(float x) {
  x = fmaxf(x, fdpp<0xB1>(x));    // quad_perm [1,0,3,2]  (xor1)
  x = fmaxf(x, fdpp<0x4E>(x));    // quad_perm [2,3,0,1]  (xor2)
  x = fmaxf(x, fdpp<0x141>(x));   // row_half_mirror
  x = fmaxf(x, fdpp<0x140>(x));   // row_mirror
  return x;
}
__device__ __forceinline__ float rowsum16(float x) {
  x += fdpp<0xB1>(x);
  x += fdpp<0x4E>(x);
  x += fdpp<0x141>(x);
  x += fdpp<0x140>(x);
  return x;
}

// ---------------- convert f32 -> f16 (+ slot-table init) ------------------
__global__ __launch_bounds__(256) void k_convert(
    const float* __restrict__ X, const float* __restrict__ Wq,
    const float* __restrict__ Wk, const float* __restrict__ Wv,
    f16* __restrict__ Xh, f16* __restrict__ Wh, int* __restrict__ tp) {
  const int SD = S_TOK * DDIM;
  const int DD = DDIM * DDIM;
  int gi = blockIdx.x * 256 + threadIdx.x;
  if (gi < NSLOT) tp[gi] = -1;
  int i4 = gi * 4;
  if (i4 < SD) {
    f32x4 v = *(const f32x4*)(X + i4);
    f16x4 h = {(f16)v[0], (f16)v[1], (f16)v[2], (f16)v[3]};
    *(f16x4*)(Xh + i4) = h;
  } else {
    int j = i4 - SD;
    int mat = j >> 18;
    const float* src = (mat == 0) ? Wq : (mat == 1 ? Wk : Wv);
    f32x4 v = *(const f32x4*)(src + (j & (DD - 1)));
    f16x4 h = {(f16)v[0], (f16)v[1], (f16)v[2], (f16)v[3]};
    *(f16x4*)(Wh + j) = h;
  }
}

// ---------------- QKV projection ------------------------------------------
// Q row-major (pre-scaled).
// K in QKT-B-frag order: tile*32768 + half*16384 + ks*1024 + lane*16 + j*2
//   holds K[tile*32 + half*16 + (lane&15)][ks*32 + (lane>>4)*8 + j]
// V in PV-B-frag order: (K*32+f)*1024 + lane*16 + j*2 holds
//   V[K*32+(lane>>4)*8+j][f*16+(lane&15)]
__global__ __launch_bounds__(256) void k_proj(
    const f16* __restrict__ Xh, const f16* __restrict__ Wh,
    f16* __restrict__ Qh, f16* __restrict__ KB, f16* __restrict__ VB) {
  __shared__ __align__(16) char Al[128 * 128];
  __shared__ __align__(16) char Bl[128 * 128];
  const int tid = threadIdx.x;
  const int w = tid >> 6, lane = tid & 63;
  const int m0 = blockIdx.x * 128;
  const int n0 = blockIdx.y * 128;
  const int wr = (w >> 1) * 64;
  const int wc = (w & 1) * 64;

  f32x4 acc[4][4];
#pragma unroll
  for (int i = 0; i < 4; ++i)
#pragma unroll
    for (int j = 0; j < 4; ++j) acc[i][j] = (f32x4){0.f, 0.f, 0.f, 0.f};

  const char* Xb = (const char*)Xh;
  const char* Wb = (const char*)Wh;

  for (int kb = 0; kb < DDIM; kb += 64) {
    __syncthreads();
#pragma unroll
    for (int i = 0; i < 4; ++i) {
      int ch = w * 4 + i;
      int srow = lane >> 3;
      int scol = ((lane & 7) * 16) ^ (srow << 4);
      gload_lds16(Xb + (size_t)(m0 + ch * 8 + srow) * 1024 + kb * 2 + scol, Al + ch * 1024);
      gload_lds16(Wb + (size_t)(n0 + ch * 8 + srow) * 1024 + kb * 2 + scol, Bl + ch * 1024);
    }
    __syncthreads();
#pragma unroll
    for (int ks = 0; ks < 2; ++ks) {
      f16x8 a[4], b[4];
#pragma unroll
      for (int mf = 0; mf < 4; ++mf) {
        int row = wr + mf * 16 + (lane & 15);
        int col = (ks * 64 + ((lane >> 4) * 16)) ^ ((row & 7) << 4);
        a[mf] = *(const f16x8*)(Al + row * 128 + col);
      }
#pragma unroll
      for (int nf = 0; nf < 4; ++nf) {
        int row = wc + nf * 16 + (lane & 15);
        int col = (ks * 64 + ((lane >> 4) * 16)) ^ ((row & 7) << 4);
        b[nf] = *(const f16x8*)(Bl + row * 128 + col);
      }
#pragma unroll
      for (int mf = 0; mf < 4; ++mf)
#pragma unroll
        for (int nf = 0; nf < 4; ++nf)
          acc[mf][nf] = __builtin_amdgcn_mfma_f32_16x16x32_f16(a[mf], b[nf], acc[mf][nf], 0, 0, 0);
    }
  }
  int mat = n0 >> 9;
  int nbase = n0 & 511;
  if (mat == 2) {
#pragma unroll
    for (int mf = 0; mf < 4; ++mf) {
      int R0 = m0 + wr + mf * 16 + (lane >> 4) * 4;   // 4-aligned token row
      int K = R0 >> 5;
      int lhi = ((R0 >> 3) & 3) * 16;
      int j0 = R0 & 7;                                // 0 or 4
#pragma unroll
      for (int nf = 0; nf < 4; ++nf) {
        int col = nbase + wc + nf * 16 + (lane & 15);
        f16x4 h = {(f16)acc[mf][nf][0], (f16)acc[mf][nf][1],
                   (f16)acc[mf][nf][2], (f16)acc[mf][nf][3]};
        *(f16x4*)((char*)VB + (size_t)(K * 32 + (col >> 4)) * 1024 +
                  (lhi + (col & 15)) * 16 + j0 * 2) = h;
      }
    }
  } else if (mat == 1) {
#pragma unroll
    for (int mf = 0; mf < 4; ++mf)
#pragma unroll
      for (int nf = 0; nf < 4; ++nf)
#pragma unroll
        for (int r = 0; r < 4; ++r) {
          int token = m0 + wr + mf * 16 + (lane >> 4) * 4 + r;
          int d = nbase + wc + nf * 16 + (lane & 15);
          size_t byte = (size_t)(token >> 5) * 32768 + (size_t)((token >> 4) & 1) * 16384
                      + (size_t)(d >> 5) * 1024
                      + (token & 15) * 16 + ((d >> 3) & 3) * 256 + (d & 7) * 2;
          *(f16*)((char*)KB + byte) = (f16)acc[mf][nf][r];
        }
  } else {
    float scale = QSCALE;
#pragma unroll
    for (int mf = 0; mf < 4; ++mf)
#pragma unroll
      for (int nf = 0; nf < 4; ++nf)
#pragma unroll
        for (int r = 0; r < 4; ++r) {
          int row = m0 + wr + mf * 16 + (lane >> 4) * 4 + r;
          int col = nbase + wc + nf * 16 + (lane & 15);
          Qh[(size_t)row * DDIM + col] = (f16)(acc[mf][nf][r] * scale);
        }
  }
}

// ---------------- causal flash attention, v13 ------------------------------
// R11 (frag-packed K/V, linear LDS, in-reg DPP softmax, P wave-private dbuf)
// + fused QK^T(it)||PV(it-1) phase + split K/V staging + counted vmcnt(4):
//   [vmcnt(4); barrier] -> STAGE_K(it+1) -> FUSED -> barrier ->
//   STAGE_V(it+1) -> SM(it)->P[it&1]
// Every stage has >= 1 full phase in flight before its wait.
__global__ __launch_bounds__(512, 2) void k_flash(
    const f16* __restrict__ Qh, const f16* __restrict__ KBg,
    const f16* __restrict__ VBg, f16* __restrict__ Opart,
    float* __restrict__ Mpart, float* __restrict__ Lpart,
    int* __restrict__ TilePart) {
  __shared__ __align__(16) char Kl[2][32768];   // K tile, frag-packed (linear)
  __shared__ __align__(16) char Vl[2][32768];   // V frag-packed [32 frags][1KB]
  __shared__ __align__(16) char Pl[8][2][1152]; // per-wave dbuf P: 16 rows x 72B

  const int tid = threadIdx.x;
  const int w = tid >> 6, lane = tid & 63;
  const int l15 = lane & 15, l4 = lane >> 4;

  int bid = blockIdx.x;
  int b = (bid & 7) * 32 + (bid >> 3);          // XCD-contiguous logical id
  int g  = (GTOT * b) >> 8;
  int g1 = (GTOT * (b + 1)) >> 8;
  int t = 0;
  while (2 * (t + 1) * (t + 2) <= g) ++t;

  const char* Kb = (const char*)KBg;
  const char* Vb = (const char*)VBg;

#define STAGEK(KB_, BI) do {                                                   \
    const char* ks_ = Kb + (size_t)((KB_) >> 5) * 32768;                       \
    _Pragma("unroll")                                                          \
    for (int i_ = 0; i_ < 4; ++i_) {                                           \
      int ch_ = w * 4 + i_;                                                    \
      gload_lds16(ks_ + ch_ * 1024 + lane * 16, Kl[BI] + ch_ * 1024);          \
    } } while (0)

#define STAGEV(KB_, BI) do {                                                   \
    const char* vs_ = Vb + (size_t)(KB_) * 1024;                               \
    _Pragma("unroll")                                                          \
    for (int i_ = 0; i_ < 4; ++i_) {                                           \
      int ch_ = w * 4 + i_;                                                    \
      gload_lds16(vs_ + ch_ * 1024 + lane * 16, Vl[BI] + ch_ * 1024);          \
    } } while (0)

// softmax of s0/s1 for kv block KB_, P into Pdst (stride-72 rows)
#define SOFTMAX(KB_, Pdst) do {                                                \
    float p0[4], p1[4], mx[4];                                                 \
    int qrb = q0 + w * 16 + l4 * 4;                                            \
    int kc = (KB_) + l15;                                                      \
    _Pragma("unroll")                                                          \
    for (int r = 0; r < 4; ++r) {                                              \
      int qr = qrb + r;                                                        \
      float x0 = (kc      <= qr) ? s0[r] : -3.0e38f;                           \
      float x1 = (kc + 16 <= qr) ? s1[r] : -3.0e38f;                           \
      p0[r] = x0; p1[r] = x1;                                                  \
      mx[r] = rowmax16(fmaxf(x0, x1));                                         \
    }                                                                          \
    bool need = (mx[0] > mreg[0] + 8.f) || (mx[1] > mreg[1] + 8.f) ||          \
                (mx[2] > mreg[2] + 8.f) || (mx[3] > mreg[3] + 8.f);            \
    if (__any(need)) {                                                         \
      float alpha[4];                                                          \
      _Pragma("unroll")                                                        \
      for (int r = 0; r < 4; ++r) {                                            \
        float mn = fmaxf(mreg[r], mx[r]);                                      \
        alpha[r] = exp2f((mreg[r] - mn) * L2E);                                \
        lreg[r] *= alpha[r];                                                   \
        mreg[r] = mn;                                                          \
      }                                                                        \
      _Pragma("unroll")                                                        \
      for (int nf = 0; nf < 32; ++nf) {                                        \
        acc[nf][0] *= alpha[0];                                                \
        acc[nf][1] *= alpha[1];                                                \
        acc[nf][2] *= alpha[2];                                                \
        acc[nf][3] *= alpha[3];                                                \
      }                                                                        \
    }                                                                          \
    _Pragma("unroll")                                                          \
    for (int r = 0; r < 4; ++r) {                                              \
      int qr = qrb + r;                                                        \
      p0[r] = (kc      <= qr) ? exp2f((p0[r] - mreg[r]) * L2E) : 0.f;          \
      p1[r] = (kc + 16 <= qr) ? exp2f((p1[r] - mreg[r]) * L2E) : 0.f;          \
    }                                                                          \
    _Pragma("unroll")                                                          \
    for (int r = 0; r < 4; ++r) {                                              \
      int row = l4 * 4 + r;                                                    \
      *(f16*)((Pdst) + row * 72 + l15 * 2)      = (f16)p0[r];                  \
      *(f16*)((Pdst) + row * 72 + 32 + l15 * 2) = (f16)p1[r];                  \
    }                                                                          \
    _Pragma("unroll")                                                          \
    for (int r = 0; r < 4; ++r)                                                \
      lreg[r] += rowsum16(p0[r] + p1[r]);                                      \
  } while (0)

// QKT only (prologue): frag-packed K -> base reg + immediate offsets
#define QKT(BUF) do {                                                          \
    s0 = (f32x4){0.f, 0.f, 0.f, 0.f};                                          \
    s1 = (f32x4){0.f, 0.f, 0.f, 0.f};                                          \
    const char* kp_ = (BUF) + lane * 16;                                       \
    __builtin_amdgcn_s_setprio(1);                                             \
    _Pragma("unroll")                                                          \
    for (int ks = 0; ks < 16; ++ks) {                                          \
      f16x8 kf0 = *(const f16x8*)(kp_ + ks * 1024);                            \
      s0 = __builtin_amdgcn_mfma_f32_16x16x32_f16(qf[ks], kf0, s0, 0, 0, 0);   \
      f16x8 kf1 = *(const f16x8*)(kp_ + 16384 + ks * 1024);                    \
      s1 = __builtin_amdgcn_mfma_f32_16x16x32_f16(qf[ks], kf1, s1, 0, 0, 0);   \
    }                                                                          \
    __builtin_amdgcn_s_setprio(0); } while (0)

// PV only (drain)
#define PV(BI) do {                                                            \
    const char* vp_ = Vl[BI] + lane * 16;                                      \
    const char* Pp_ = Pw + (BI) * 1152;                                        \
    f16x8 pa_ = *(const f16x8*)(Pp_ + l15 * 72 + l4 * 16);                     \
    __builtin_amdgcn_s_setprio(1);                                             \
    _Pragma("unroll")                                                          \
    for (int nf = 0; nf < 32; ++nf) {                                          \
      f16x8 vb_ = *(const f16x8*)(vp_ + nf * 1024);                            \
      acc[nf] = __builtin_amdgcn_mfma_f32_16x16x32_f16(pa_, vb_, acc[nf], 0, 0, 0); \
    }                                                                          \
    __builtin_amdgcn_s_setprio(0); } while (0)

// FUSED: QK^T(it) from KBUF interleaved with PV(it-1) from Vl[VBI]/P[VBI]
#define FUSED(KBUF, VBI) do {                                                  \
    s0 = (f32x4){0.f, 0.f, 0.f, 0.f};                                          \
    s1 = (f32x4){0.f, 0.f, 0.f, 0.f};                                          \
    const char* kp_ = (KBUF) + lane * 16;                                      \
    const char* vp_ = Vl[VBI] + lane * 16;                                     \
    const char* Pp_ = Pw + (VBI) * 1152;                                       \
    f16x8 pa_ = *(const f16x8*)(Pp_ + l15 * 72 + l4 * 16);                     \
    __builtin_amdgcn_s_setprio(1);                                             \
    _Pragma("unroll")                                                          \
    for (int ks = 0; ks < 16; ++ks) {                                          \
      f16x8 kf0 = *(const f16x8*)(kp_ + ks * 1024);                            \
      s0 = __builtin_amdgcn_mfma_f32_16x16x32_f16(qf[ks], kf0, s0, 0, 0, 0);   \
      f16x8 vb0 = *(const f16x8*)(vp_ + (2 * ks) * 1024);                      \
      acc[2 * ks] = __builtin_amdgcn_mfma_f32_16x16x32_f16(pa_, vb0, acc[2 * ks], 0, 0, 0); \
      f16x8 kf1 = *(const f16x8*)(kp_ + 16384 + ks * 1024);                    \
      s1 = __builtin_amdgcn_mfma_f32_16x16x32_f16(qf[ks], kf1, s1, 0, 0, 0);   \
      f16x8 vb1 = *(const f16x8*)(vp_ + (2 * ks + 1) * 1024);                  \
      acc[2 * ks + 1] = __builtin_amdgcn_mfma_f32_16x16x32_f16(pa_, vb1, acc[2 * ks + 1], 0, 0, 0); \
    }                                                                          \
    __builtin_amdgcn_s_setprio(0); } while (0)

  char* Pw = (char*)Pl + (size_t)w * 2304;

  while (g < g1) {
    int Ct  = 2 * t * (t + 1);
    int Ct1 = 2 * (t + 1) * (t + 2);
    int gend = min(g1, Ct1);
    int n = gend - g;
    int kb0 = (g - Ct) * 32;
    int q0 = t * 128;
    int slot = b + t;

    // Q fragments: rows q0 + w*16 + l15, full D
    f16x8 qf[16];
    {
      const f16* qp = Qh + (size_t)(q0 + w * 16 + l15) * DDIM + l4 * 8;
#pragma unroll
      for (int ks = 0; ks < 16; ++ks) qf[ks] = *(const f16x8*)(qp + ks * 32);
    }
    f32x4 acc[32];
#pragma unroll
    for (int i = 0; i < 32; ++i) acc[i] = (f32x4){0.f, 0.f, 0.f, 0.f};
    float mreg[4], lreg[4];
#pragma unroll
    for (int r = 0; r < 4; ++r) { mreg[r] = -3.0e38f; lreg[r] = 0.f; }
    f32x4 s0, s1;

    // ---- prologue: tile 0 staged+waited; K(1)/V(1) issued around QKT/SM(0)
    STAGEK(kb0, 0);
    STAGEV(kb0, 0);
    asm volatile("s_waitcnt vmcnt(0)" ::: "memory");
    __builtin_amdgcn_s_barrier();
    if (n > 1) STAGEK(kb0 + 32, 1);
    QKT(Kl[0]);
    SOFTMAX(kb0, Pw);                           // -> P[0]
    asm volatile("s_waitcnt lgkmcnt(0)" ::: "memory");
    if (n > 1) STAGEV(kb0 + 32, 1);

    // ---- steady state
    for (int it = 1; it < n; ++it) {
      asm volatile("s_waitcnt vmcnt(4)" ::: "memory");  // K(it) done; V(it) may fly
      __builtin_amdgcn_s_barrier();                     // publish K(it)
      if (it + 1 < n) STAGEK(kb0 + (it + 1) * 32, (it + 1) & 1);
      FUSED(Kl[it & 1], (it - 1) & 1);                  // QKT(it) || PV(it-1)
      __builtin_amdgcn_s_barrier();                     // V(it-1)/K(it) reads done
      if (it + 1 < n) STAGEV(kb0 + (it + 1) * 32, (it + 1) & 1);
      SOFTMAX(kb0 + it * 32, Pw + (it & 1) * 1152);
      asm volatile("s_waitcnt lgkmcnt(0)" ::: "memory"); // P committed
    }

    // ---- drain: PV(n-1)
    asm volatile("s_waitcnt vmcnt(0)" ::: "memory");    // V(n-1) landed
    __builtin_amdgcn_s_barrier();                       // publish V(n-1)
    PV((n - 1) & 1);
    __builtin_amdgcn_s_barrier();                       // reads done pre-next-tile

    // ---- epilogue: all stats in-reg (DPP-reduced => uniform per row group)
    {
      float inv[4];
#pragma unroll
      for (int r = 0; r < 4; ++r) inv[r] = (lreg[r] > 0.f) ? 1.f / lreg[r] : 0.f;
      f16* op = Opart + (size_t)slot * (128 * 512);
      int rowb = w * 16 + l4 * 4;
#pragma unroll
      for (int nf = 0; nf < 32; ++nf) {
        int col = nf * 16 + l15;
#pragma unroll
        for (int r = 0; r < 4; ++r)
          op[(size_t)(rowb + r) * 512 + col] = (f16)(acc[nf][r] * inv[r]);
      }
      if (l15 == 0) {
#pragma unroll
        for (int r = 0; r < 4; ++r) {
          Mpart[slot * 128 + rowb + r] = mreg[r];
          Lpart[slot * 128 + rowb + r] = lreg[r];
        }
      }
      if (tid == 0) TilePart[slot] = t;
    }
    g = gend;
    ++t;
  }
#undef STAGEK
#undef STAGEV
#undef SOFTMAX
#undef QKT
#undef PV
#undef FUSED
}

// ---------------- combine partials -> out --------------------------------
__global__ __launch_bounds__(256) void k_reduce(
    const f16* __restrict__ Opart, const float* __restrict__ Mpart,
    const float* __restrict__ Lpart, const int* __restrict__ TilePart,
    float* __restrict__ out) {
  __shared__ int tp[NSLOT];
  __shared__ int sl[16];
  __shared__ int scnt;
  int tid = threadIdx.x;
  int t = blockIdx.x >> 2, rg = blockIdx.x & 3;
  for (int s = tid; s < NSLOT; s += 256) tp[s] = TilePart[s];
  __syncthreads();
  if (tid == 0) {
    int c = 0;
    for (int s = 0; s < NSLOT; ++s)
      if (tp[s] == t && c < 16) sl[c++] = s;
    scnt = c;
  }
  __syncthreads();
  int cnt = scnt;
  int rowIn = rg * 32 + (tid >> 3);
  int row = t * 128 + rowIn;
  int col0 = (tid & 7) * 64;

  float M = -3.0e38f;
  for (int i = 0; i < cnt; ++i) M = fmaxf(M, Mpart[sl[i] * 128 + rowIn]);
  float a[64];
#pragma unroll
  for (int j = 0; j < 64; ++j) a[j] = 0.f;
  float denom = 0.f;
  for (int i = 0; i < cnt; ++i) {
    int s = sl[i];
    float m = Mpart[s * 128 + rowIn];
    float l = Lpart[s * 128 + rowIn];
    float wgt = exp2f((m - M) * L2E) * l;
    denom += wgt;
    const f16* op = Opart + (size_t)s * 65536 + rowIn * 512 + col0;
#pragma unroll
    for (int v = 0; v < 8; ++v) {
      f16x8 x = *(const f16x8*)(op + v * 8);
#pragma unroll
      for (int j = 0; j < 8; ++j) a[v * 8 + j] += wgt * (float)x[j];
    }
  }
  float inv = (denom > 0.f) ? 1.f / denom : 0.f;
  float* o = out + (size_t)row * 512 + col0;
#pragma unroll
  for (int j = 0; j < 64; ++j) o[j] = a[j] * inv;
}

extern "C" void kernel_launch(void* const* d_in, const int* in_sizes, int n_in,
                              void* d_out, int out_size, void* d_ws, size_t ws_size,
                              hipStream_t stream) {
  const float* X  = (const float*)d_in[0];
  const float* Wq = (const float*)d_in[2];
  const float* Wk = (const float*)d_in[3];
  const float* Wv = (const float*)d_in[4];
  float* out = (float*)d_out;

  char* ws = (char*)d_ws;
  f16*   Opart = (f16*)(ws);                               // 40 MiB
  float* Mpart = (float*)(ws + (40u << 20));               // 160 KiB
  float* Lpart = (float*)(ws + (41u << 20));               // 160 KiB
  int*   TileP = (int*)(ws + (42u << 20));                 // 1.25 KiB
  f16* Qh = (f16*)(ws + (43u << 20));                      // 8 MiB (pre-scaled)
  f16* KB = (f16*)(ws + (51u << 20));                      // 8 MiB QKT-frag-packed
  f16* VB = (f16*)(ws + (59u << 20));                      // 8 MiB PV-frag-packed
  f16* Xh = (f16*)(ws + (67u << 20));                      // 8 MiB
  f16* Wh = (f16*)(ws + (75u << 20));                      // 1.5 MiB

  k_convert<<<4864, 256, 0, stream>>>(X, Wq, Wk, Wv, Xh, Wh, TileP);
  dim3 gp(64, 12);
  k_proj<<<gp, 256, 0, stream>>>(Xh, Wh, Qh, KB, VB);
  k_flash<<<256, 512, 0, stream>>>(Qh, KB, VB, Opart, Mpart, Lpart, TileP);
  k_reduce<<<256, 256, 0, stream>>>(Opart, Mpart, Lpart, TileP, out);
}